// Round 5
// baseline (2336.173 us; speedup 1.0000x reference)
//
#include <hip/hip_runtime.h>
#include <math.h>

#define Bb 64
#define Ll 512
#define Dd 512
#define Ff 2048
#define Ee 8

typedef _Float16 half_t;
typedef _Float16 half8 __attribute__((ext_vector_type(8)));
typedef float f32x4 __attribute__((ext_vector_type(4)));

// ws layout (halves): W1t [E][F][D] at 0 ; W2t [E][D][F] at W2T_OFF ;
// xh (fp16 x in A-fragment order) at XH_OFF
#define W2T_OFF ((size_t)Ee * Dd * Ff)
#define XH_OFF  ((size_t)2 * Ee * Dd * Ff)

__device__ __forceinline__ void dma16(const half_t* g, half_t* l) {
    // global -> LDS direct DMA, 16B per lane; LDS dst = uniform base + lane*16
    __builtin_amdgcn_global_load_lds((const __attribute__((address_space(1))) void*)g,
                                     (__attribute__((address_space(3))) void*)l, 16, 0, 0);
}
__device__ __forceinline__ void dma16f(const float* g, float* l) {
    __builtin_amdgcn_global_load_lds((const __attribute__((address_space(1))) void*)g,
                                     (__attribute__((address_space(3))) void*)l, 16, 0, 0);
}

// Counted-vmcnt barrier discipline: never drain vmcnt(0) mid-stream.
#define VWAIT(n)  asm volatile("s_waitcnt vmcnt(" #n ")" ::: "memory")
#define VLWAIT(n) asm volatile("s_waitcnt vmcnt(" #n ") lgkmcnt(0)" ::: "memory")
#define SB() __builtin_amdgcn_sched_barrier(0)
#define BAR() do { __builtin_amdgcn_s_barrier();                 \
                   asm volatile("" ::: "memory");                \
                   __builtin_amdgcn_sched_barrier(0); } while (0)

// ---------------- prep: fp32 [R][C] -> fp16 [C][R] transpose ----------------
__global__ __launch_bounds__(256)
void prep_transpose(const float* __restrict__ w1, const float* __restrict__ w2,
                    half_t* __restrict__ ws)
{
    __shared__ half_t T[64 * 72];
    int bid = blockIdx.x;
    const float* src; half_t* dst; int R, C, r0, c0;
    if (bid < 2048) {            // W1 per e: R=512(d), C=2048(f): 8 x 32 tiles
        int e = bid >> 8, t = bid & 255;
        r0 = (t >> 5) * 64; c0 = (t & 31) * 64;
        src = w1 + (size_t)e * Dd * Ff;
        dst = ws + (size_t)e * Ff * Dd;
        R = Dd; C = Ff;
    } else {                     // W2 per e: R=2048(f), C=512(d): 32 x 8 tiles
        bid -= 2048;
        int e = bid >> 8, t = bid & 255;
        r0 = (t >> 3) * 64; c0 = (t & 7) * 64;
        src = w2 + (size_t)e * Ff * Dd;
        dst = ws + W2T_OFF + (size_t)e * Dd * Ff;
        R = Ff; C = Dd;
    }
    const int cx = threadIdx.x & 63, ry = threadIdx.x >> 6;
    #pragma unroll
    for (int j = 0; j < 16; ++j) {
        int r = ry * 16 + j;
        T[cx * 72 + r] = (half_t)src[(size_t)(r0 + r) * C + c0 + cx];
    }
    __syncthreads();
    const int rx = threadIdx.x & 7;
    #pragma unroll
    for (int it = 0; it < 2; ++it) {
        int cr = (threadIdx.x >> 3) + it * 32;
        *(half8*)&dst[(size_t)(c0 + cr) * R + r0 + rx * 8] = *(half8*)&T[cr * 72 + rx * 8];
    }
}

// ---------------- xprep: x fp32 -> fp16 in A-fragment order ----------------
// Block index blk = (b*32 + tg)*16 + ksg  (tg = token-group of 16, ksg = k/32)
// Within block: slot lane = nl + 16*q holds token tg*16+nl, k = ksg*32+q*8..+8
__global__ __launch_bounds__(256)
void xprep(const float* __restrict__ x, half_t* __restrict__ ws)
{
    const size_t i = (size_t)blockIdx.x * 256 + threadIdx.x;  // half8 slot index
    const int grp = (int)(i & 63);
    const size_t blk = i >> 6;
    const int ksg = (int)(blk & 15);
    const size_t btg = blk >> 4;
    const int tg = (int)(btg & 31);
    const int b  = (int)(btg >> 5);
    const int nl = grp & 15, q = grp >> 4;
    const int token = tg * 16 + nl;
    const int k0 = ksg * 32 + q * 8;
    const float* src = x + (size_t)(b * Ll + token) * Dd + k0;
    const f32x4 u0 = *(const f32x4*)src;
    const f32x4 u1 = *(const f32x4*)(src + 4);
    half8 h;
    h[0]=(half_t)u0[0]; h[1]=(half_t)u0[1]; h[2]=(half_t)u0[2]; h[3]=(half_t)u0[3];
    h[4]=(half_t)u1[0]; h[5]=(half_t)u1[1]; h[6]=(half_t)u1[2]; h[7]=(half_t)u1[3];
    *(half8*)&ws[XH_OFF + i * 8] = h;
}

// ---------------- main fused MoE ----------------
// Block = (b, 64-token tile), 512 thr / 8 waves (2m x 4n), 1 block/CU.
// 2m x 4n wave retile: each B-fragment ds_read feeds TWO MFMAs (ma=0,1) ->
// block-wide ds_read_b128 per step drops 128 -> 64+eps (the r1 structure's
// dominant cost). x A-fragments stream from L2 (fp16 fragment-order ws copy,
// 1KB coalesced per wave-load) into a 2-deep register buffer - no 128-VGPR
// persistent afrag. r1's verified 3-buffer counted-vmcnt schedule kept; A-
// loads pinned between sched_barrier(0) so vmcnt arithmetic stays exact.
__global__ __launch_bounds__(512, 2)
void moe_main(const float* __restrict__ logits,
              const int* __restrict__ masks, const half_t* __restrict__ ws,
              const float* __restrict__ b1, const float* __restrict__ b2,
              float* __restrict__ out)
{
    __shared__ half_t Wbuf[3][128 * 128];   // 3 x 32KB rotating weight tiles
    __shared__ half_t Hs[64 * 128];         // 16KB hidden tile
    __shared__ float  Bs[128];              // b1 chunk for current fci

    const int tid  = threadIdx.x;
    const int wv   = tid >> 6;
    const int lane = tid & 63;
    const int nl   = lane & 15;
    const int q    = lane >> 4;
    const int mw   = wv >> 2;     // 0..1 token-half (32 tokens)
    const int nw   = wv & 3;      // 0..3 n-quarter (32 rows)
    const int rl   = lane >> 4;   // DMA row-within-4
    const int pcl  = lane & 15;   // DMA 16B slot

    const int bid = blockIdx.x;
    const int rk  = bid >> 3;            // LPT rank (heavy rows first)
    const int l0  = (bid & 7) * 64;      // tiles of one b spread across XCDs

    // ---- LPT rank -> b: rk-th heaviest batch row ----
    int b;
    {
        int cj = 0;
        #pragma unroll
        for (int e2 = 0; e2 < Ee; ++e2) cj += (masks[lane * Ee + e2] == 1);
        int rj = 0;
        for (int k = 0; k < Bb; ++k) {
            const int ck = __shfl(cj, k);
            rj += (ck > cj) || (ck == cj && k < lane);
        }
        const unsigned long long mword = __ballot(rj == rk);
        b = (int)__builtin_ctzll(mword);
    }

    // ---- gates: uniform softmax math; lane holds gate[lane&7] ----
    float mx = -1e30f;
    #pragma unroll
    for (int e = 0; e < Ee; ++e) mx = fmaxf(mx, logits[b * Ee + e]);
    float s = 0.f, gs = 0.f;
    unsigned am = 0u;
    #pragma unroll
    for (int e = 0; e < Ee; ++e) {
        const float ex = expf(logits[b * Ee + e] - mx);
        s += ex;
        if (masks[b * Ee + e] == 1) { gs += ex; am |= (1u << e); }
    }
    const int el = lane & 7;
    const float myg = ((am >> el) & 1u)
        ? expf(logits[b * Ee + el] - mx) / (gs + 1e-9f * s) : 0.f;
    float ge[Ee];                    // static-indexed copy for final epilogue
    #pragma unroll
    for (int e = 0; e < Ee; ++e) ge[e] = __shfl(myg, e);

    // ---- x A-fragment stream base (fp16 fragment-order in ws) ----
    // token-group tg0 = l0/16 + mw*2 (+ma); block (b*32+tg)*16 + kstep
    const half_t* xbase = ws + XH_OFF
        + ((size_t)(b * 32 + (l0 >> 4) + mw * 2) * 16) * 512 + lane * 8;

    half8 aregA[8], aregB[8];   // [ma*4+ks] double-buffered A-frags (one kc each)
    auto aload = [&](int kc, half8* dst) {
        #pragma unroll
        for (int ma = 0; ma < 2; ++ma)
            #pragma unroll
            for (int ks = 0; ks < 4; ++ks)
                dst[ma * 4 + ks] = *(const half8*)(xbase + ma * 8192 + (kc * 4 + ks) * 512);
    };

    f32x4 oacc[16];
    #pragma unroll
    for (int i = 0; i < 16; ++i) oacc[i] = (f32x4){0.f, 0.f, 0.f, 0.f};

    auto stageT = [&](const half_t* src, int ld, half_t* dst) {
        #pragma unroll
        for (int ss = 0; ss < 4; ++ss) {
            const int row = wv * 16 + ss * 4 + rl;
            const int c = pcl ^ (row & 15);
            dma16(src + (size_t)row * ld + c * 8, dst + (wv * 16 + ss * 4) * 128);
        }
    };
    // Phase A: wave owns tokens [mw*32,+32) x f-rows [nw*32,+32); B-frag reused 2x
    auto computeA = [&](const half8* ar, const half_t* Wb, f32x4* hc) {
        #pragma unroll
        for (int ks = 0; ks < 4; ++ks) {
            #pragma unroll
            for (int nf = 0; nf < 2; ++nf) {
                const int row = nw * 32 + nf * 16 + nl;
                const half8 bf = *(const half8*)&Wb[row * 128 + (((ks * 4 + q) ^ nl) * 8)];
                hc[0 + nf] = __builtin_amdgcn_mfma_f32_16x16x32_f16(ar[ks],     bf, hc[0 + nf], 0, 0, 0);
                hc[2 + nf] = __builtin_amdgcn_mfma_f32_16x16x32_f16(ar[4 + ks], bf, hc[2 + nf], 0, 0, 0);
            }
        }
    };
    // Phase B: wave owns tokens [mw*32,+32) x d-rows [nw*32,+32) of each nc
    auto computeB = [&](const half8* ha, const half_t* Wb, f32x4* oc) {
        #pragma unroll
        for (int ks = 0; ks < 4; ++ks) {
            #pragma unroll
            for (int t = 0; t < 2; ++t) {
                const int lr = nw * 32 + t * 16 + nl;
                const half8 bf = *(const half8*)&Wb[lr * 128 + (((ks * 4 + q) ^ nl) * 8)];
                oc[0 + t] = __builtin_amdgcn_mfma_f32_16x16x32_f16(ha[ks],     bf, oc[0 + t], 0, 0, 0);
                oc[2 + t] = __builtin_amdgcn_mfma_f32_16x16x32_f16(ha[4 + ks], bf, oc[2 + t], 0, 0, 0);
            }
        }
    };

    int cur = 0;
    unsigned rem = am;
    if (rem) {  // prologue: stage kc0 (+bias), kc1; load aregA(kc0)
        const int e0 = (int)__builtin_ctz(rem);
        const half_t* W1p = ws + (size_t)e0 * Ff * Dd;
        asm volatile("s_waitcnt vmcnt(0)" ::: "memory");
        stageT(W1p,       Dd, Wbuf[0]);
        if (lane < 32) dma16f(b1 + (size_t)e0 * Ff + lane * 4, Bs);
        stageT(W1p + 128, Dd, Wbuf[1]);
        SB(); aload(0, aregA); SB();
        VWAIT(12);   // retire kc0 tile + bias; kc1 dma + aregA stay in flight
        BAR();
    }

    while (rem) {
        const int e = (int)__builtin_ctz(rem); rem &= rem - 1u;
        const int en = rem ? (int)__builtin_ctz(rem) : -1;
        const float g = __shfl(myg, e);
        const half_t* W1te = ws + (size_t)e * Ff * Dd;            // [F][D]
        const half_t* W2te = ws + W2T_OFF + (size_t)e * Dd * Ff;  // [D][F]
        const half_t* W1nx = (en >= 0) ? ws + (size_t)en * Ff * Dd : W1te;
        const float*  b1nx = (en >= 0) ? b1 + (size_t)en * Ff : b1;

        #pragma unroll 1
        for (int fci = 0; fci < 16; ++fci) {
            const int f0 = fci * 128;
            const half_t* WA = W1te + (size_t)f0 * Dd;  // + kc*128 col offset
            const half_t* WB = W2te + f0;               // + nc*128*Ff row offset
            const bool hn = (fci < 15) || (en >= 0);
            const half_t* An = (fci < 15) ? (WA + (size_t)128 * Dd) : W1nx;
            const float*  bn = (fci < 15) ? (b1 + (size_t)e * Ff + f0 + 128) : b1nx;

            f32x4 hacc[4];   // [ma*2+nf]
            #pragma unroll
            for (int i = 0; i < 4; ++i) hacc[i] = (f32x4){0.f, 0.f, 0.f, 0.f};

            // ---------- Phase A: 4 K-chunks of 128 ----------
            { half_t* Wp = Wbuf[cur ? cur - 1 : 2];            // kc0: stage A(kc2)
              stageT(WA + 2 * 128, Dd, Wp);
              SB(); aload(1, aregB); SB();
              computeA(aregA, Wbuf[cur], hacc);
              VWAIT(12); BAR(); cur = (cur == 2) ? 0 : cur + 1; }
            { half_t* Wp = Wbuf[cur ? cur - 1 : 2];            // kc1: stage A(kc3)
              stageT(WA + 3 * 128, Dd, Wp);
              SB(); aload(2, aregA); SB();
              computeA(aregB, Wbuf[cur], hacc);
              VWAIT(12); BAR(); cur = (cur == 2) ? 0 : cur + 1; }
            { half_t* Wp = Wbuf[cur ? cur - 1 : 2];            // kc2: stage B(nc0)
              stageT(WB, Ff, Wp);
              SB(); aload(3, aregB); SB();
              computeA(aregA, Wbuf[cur], hacc);
              VWAIT(12); BAR(); cur = (cur == 2) ? 0 : cur + 1; }
            { half_t* Wp = Wbuf[cur ? cur - 1 : 2];            // kc3: stage B(nc1)
              stageT(WB + (size_t)128 * Ff, Ff, Wp);
              computeA(aregB, Wbuf[cur], hacc);
              // epilogue A: bias + gelu + gate -> Hs (swizzled A-layout)
              #pragma unroll
              for (int ma = 0; ma < 2; ++ma)
                  #pragma unroll
                  for (int nf = 0; nf < 2; ++nf) {
                      const int fl = nw * 32 + nf * 16 + nl;
                      const float bv = Bs[fl];
                      #pragma unroll
                      for (int r = 0; r < 4; ++r) {
                          const int m = mw * 32 + ma * 16 + q * 4 + r;
                          const float v  = hacc[ma * 2 + nf][r] + bv;
                          const float gl = 0.5f * v * (1.f + erff(v * 0.70710678118654752f));
                          const int blk = (fl >> 3) ^ (m & 15);
                          Hs[m * 128 + blk * 8 + (fl & 7)] = (half_t)(g * gl);
                      }
                  }
              VLWAIT(4); BAR(); cur = (cur == 2) ? 0 : cur + 1; }

            // ---------- Phase B: 4 n-chunks of 128 ----------
            half8 ha[8];   // [ma*4+ks]
            { half_t* Wp = Wbuf[cur ? cur - 1 : 2];            // nc0: stage B(nc2)
              #pragma unroll
              for (int ma = 0; ma < 2; ++ma)
                  #pragma unroll
                  for (int ks = 0; ks < 4; ++ks)
                      ha[ma * 4 + ks] = *(const half8*)&Hs[(mw * 32 + ma * 16 + nl) * 128
                                                           + (((ks * 4 + q) ^ nl) * 8)];
              stageT(WB + (size_t)256 * Ff, Ff, Wp);
              computeB(ha, Wbuf[cur], &oacc[0]);
              VWAIT(4); BAR(); cur = (cur == 2) ? 0 : cur + 1; }
            { half_t* Wp = Wbuf[cur ? cur - 1 : 2];            // nc1: stage B(nc3)
              stageT(WB + (size_t)384 * Ff, Ff, Wp);
              computeB(ha, Wbuf[cur], &oacc[4]);
              VWAIT(4); BAR(); cur = (cur == 2) ? 0 : cur + 1; }
            { half_t* Wp = Wbuf[cur ? cur - 1 : 2];            // nc2: stage next A(kc0)+bias
              if (hn) {
                  stageT(An, Dd, Wp);
                  if (lane < 32) dma16f(bn + lane * 4, Bs);
              }
              computeB(ha, Wbuf[cur], &oacc[8]);
              if (hn) { VWAIT(5); } else { VWAIT(0); }
              BAR(); cur = (cur == 2) ? 0 : cur + 1; }
            { half_t* Wp = Wbuf[cur ? cur - 1 : 2];            // nc3: stage next A(kc1) + aregA(kc0)
              if (hn) {
                  stageT(An + 128, Dd, Wp);
                  SB(); aload(0, aregA); SB();
              }
              computeB(ha, Wbuf[cur], &oacc[12]);
              if (hn) { VWAIT(12); } else { VWAIT(0); }
              BAR(); cur = (cur == 2) ? 0 : cur + 1; }
        }
    }

    // ---- epilogue: add sum_e gate[e]*b2[e,:] and store fp32 ----
    #pragma unroll
    for (int ncc = 0; ncc < 4; ++ncc) {
        #pragma unroll
        for (int ma = 0; ma < 2; ++ma)
            #pragma unroll
            for (int t = 0; t < 2; ++t) {
                const int dcol = ncc * 128 + nw * 32 + t * 16 + nl;
                float bb = 0.f;
                #pragma unroll
                for (int e = 0; e < Ee; ++e) bb += ge[e] * b2[e * Dd + dcol];
                const f32x4 v = oacc[ncc * 4 + ma * 2 + t];
                const size_t base = (size_t)(b * Ll + l0 + mw * 32 + ma * 16 + q * 4) * Dd + dcol;
                out[base]          = v[0] + bb;
                out[base + Dd]     = v[1] + bb;
                out[base + 2 * Dd] = v[2] + bb;
                out[base + 3 * Dd] = v[3] + bb;
            }
    }
}

__global__ void moe_loss(const float* __restrict__ logits, const int* __restrict__ masks,
                         float* __restrict__ loss_out)
{
    const int b = threadIdx.x;   // 64 threads = 1 wave
    float lg[Ee];
    float mx = -1e30f;
    #pragma unroll
    for (int e = 0; e < Ee; ++e) { lg[e] = logits[b * Ee + e]; mx = fmaxf(mx, lg[e]); }
    float s = 0.f;
    #pragma unroll
    for (int e = 0; e < Ee; ++e) { float ex = expf(lg[e] - mx); s += ex; lg[e] = ex; }
    float rs = 0.f;
    #pragma unroll
    for (int e = 0; e < Ee; ++e) if (masks[b * Ee + e] == 1) rs += lg[e] / s;
    #pragma unroll
    for (int off = 32; off > 0; off >>= 1) rs += __shfl_down(rs, off);
    if (b == 0) {
        const float t = 1.f - rs / (float)Bb;
        loss_out[0] = t * t;
    }
}

extern "C" void kernel_launch(void* const* d_in, const int* in_sizes, int n_in,
                              void* d_out, int out_size, void* d_ws, size_t ws_size,
                              hipStream_t stream)
{
    const float* x      = (const float*)d_in[0];
    const float* logits = (const float*)d_in[1];
    const int*   masks  = (const int*)d_in[2];
    const float* w1     = (const float*)d_in[3];
    const float* b1     = (const float*)d_in[4];
    const float* w2     = (const float*)d_in[5];
    const float* b2     = (const float*)d_in[6];
    float* out = (float*)d_out;
    half_t* ws = (half_t*)d_ws;

    hipLaunchKernelGGL(prep_transpose, dim3(4096), dim3(256), 0, stream, w1, w2, ws);
    hipLaunchKernelGGL(xprep, dim3(8192), dim3(256), 0, stream, x, ws);
    hipLaunchKernelGGL(moe_main, dim3(512), dim3(512), 0, stream,
                       logits, masks, ws, b1, b2, out);
    hipLaunchKernelGGL(moe_loss, dim3(1), dim3(64), 0, stream,
                       logits, masks, out + (size_t)Bb * Ll * Dd);
}